// Round 1
// baseline (97.101 us; speedup 1.0000x reference)
//
#include <hip/hip_runtime.h>

#define BD 4096   // rows
#define CD 256    // codes
#define DD 128    // dim
#define ROWS 16   // rows per block
#define CT 64     // codes per LDS tile
#define PAD 132   // padded LDS row stride (floats); 132*4B keeps float4 alignment

__global__ __launch_bounds__(256) void rq_fused(
    const float* __restrict__ x,
    const float* __restrict__ pq,
    const float* __restrict__ codes,
    float* __restrict__ out)   // [quantized BD*DD | indices BD | loss 1]
{
    __shared__ float xc_s[ROWS * PAD];
    __shared__ float code_s[CT * PAD];
    __shared__ float row_c[ROWS], row_s[ROWS], row_invn[ROWS];
    __shared__ int   row_idx[ROWS];

    const int tid  = threadIdx.x;
    const int wave = tid >> 6;
    const int lane = tid & 63;
    const int row0 = blockIdx.x * ROWS;
    const float INV_SQRT_D = 0.088388347648318447f;  // 1/sqrt(128)

    // ---------- Phase A: per-row rotation  xc = R^T x (rank-2 form) ----------
    // wave w handles rows 4w..4w+3; each lane holds 2 elements (float2).
    #pragma unroll
    for (int rr = 0; rr < 4; ++rr) {
        const int r = wave * 4 + rr;
        const size_t grow = (size_t)(row0 + r);
        const float2 xv = ((const float2*)(x  + grow * DD))[lane];
        const float2 pv = ((const float2*)(pq + grow * DD))[lane];
        float s0 = pv.x * pv.x + pv.y * pv.y;   // ||pq||^2
        float s1 = pv.x + pv.y;                 // sum pq
        float s2 = xv.x + xv.y;                 // sum x
        float s3 = pv.x * xv.x + pv.y * xv.y;   // pq . x
        #pragma unroll
        for (int m = 32; m > 0; m >>= 1) {
            s0 += __shfl_xor(s0, m);
            s1 += __shfl_xor(s1, m);
            s2 += __shfl_xor(s2, m);
            s3 += __shfl_xor(s3, m);
        }
        const float n    = sqrtf(s0);
        const float invn = 1.0f / fmaxf(n, 1e-6f);     // u = pq * invn
        const float b = s2 * INV_SQRT_D;               // v.x
        const float a = s3 * invn;                     // u.x
        const float c = s1 * invn * INV_SQRT_D;        // u.v
        const float s = 1.0f / (1.0f + c + 1e-6f);
        // R^T x = x + u*(-b + s(cb - a)) + v*(a + s(ca - b))
        const float au = -b + s * (c * b - a);
        const float av =  a + s * (c * a - b);
        const float ux = pv.x * invn, uy = pv.y * invn;
        xc_s[r * PAD + 2 * lane]     = xv.x + au * ux + av * INV_SQRT_D;
        xc_s[r * PAD + 2 * lane + 1] = xv.y + au * uy + av * INV_SQRT_D;
        if (lane == 0) { row_c[r] = c; row_s[r] = s; row_invn[r] = invn; }
    }
    __syncthreads();

    // ---------- Phase B: distances + argmin ----------
    // thread -> (rowgroup rg: rows 2rg,2rg+1) x (codegroup cg: codes cg,cg+32 per tile)
    const int rg = tid >> 5;   // 0..7
    const int cg = tid & 31;   // 0..31
    float bestv0 = 3.4e38f, bestv1 = 3.4e38f;
    int   besti0 = 0,        besti1 = 0;

    for (int t = 0; t < CD / CT; ++t) {
        // stage 64 codes to LDS, coalesced
        const float4* src = ((const float4*)codes) + (size_t)t * (CT * DD / 4);
        #pragma unroll
        for (int k = 0; k < (CT * DD / 4) / 256; ++k) {   // 8 float4 per thread
            const int f  = k * 256 + tid;
            const int cr = f >> 5, cc = f & 31;
            *(float4*)(code_s + cr * PAD + cc * 4) = src[f];
        }
        __syncthreads();

        float acc00 = 0.f, acc01 = 0.f, acc10 = 0.f, acc11 = 0.f;
        const float* xr0 = xc_s + (2 * rg) * PAD;
        const float* xr1 = xc_s + (2 * rg + 1) * PAD;
        const float* ca  = code_s + cg * PAD;
        const float* cb  = code_s + (cg + 32) * PAD;
        #pragma unroll
        for (int d4 = 0; d4 < 32; ++d4) {
            const float4 xa = *(const float4*)(xr0 + d4 * 4);
            const float4 xb = *(const float4*)(xr1 + d4 * 4);
            const float4 va = *(const float4*)(ca  + d4 * 4);
            const float4 vb = *(const float4*)(cb  + d4 * 4);
            float dx;
            dx = xa.x - va.x; acc00 = fmaf(dx, dx, acc00);
            dx = xa.y - va.y; acc00 = fmaf(dx, dx, acc00);
            dx = xa.z - va.z; acc00 = fmaf(dx, dx, acc00);
            dx = xa.w - va.w; acc00 = fmaf(dx, dx, acc00);
            dx = xa.x - vb.x; acc01 = fmaf(dx, dx, acc01);
            dx = xa.y - vb.y; acc01 = fmaf(dx, dx, acc01);
            dx = xa.z - vb.z; acc01 = fmaf(dx, dx, acc01);
            dx = xa.w - vb.w; acc01 = fmaf(dx, dx, acc01);
            dx = xb.x - va.x; acc10 = fmaf(dx, dx, acc10);
            dx = xb.y - va.y; acc10 = fmaf(dx, dx, acc10);
            dx = xb.z - va.z; acc10 = fmaf(dx, dx, acc10);
            dx = xb.w - va.w; acc10 = fmaf(dx, dx, acc10);
            dx = xb.x - vb.x; acc11 = fmaf(dx, dx, acc11);
            dx = xb.y - vb.y; acc11 = fmaf(dx, dx, acc11);
            dx = xb.z - vb.z; acc11 = fmaf(dx, dx, acc11);
            dx = xb.w - vb.w; acc11 = fmaf(dx, dx, acc11);
        }
        // fold, ascending index order for first-min tie-break
        const int i0 = t * CT + cg;
        const int i1 = t * CT + cg + 32;
        if (acc00 < bestv0) { bestv0 = acc00; besti0 = i0; }
        if (acc01 < bestv0) { bestv0 = acc01; besti0 = i1; }
        if (acc10 < bestv1) { bestv1 = acc10; besti1 = i0; }
        if (acc11 < bestv1) { bestv1 = acc11; besti1 = i1; }
        __syncthreads();
    }
    // reduce argmin over the 32 cg lanes (contiguous within a wave)
    #pragma unroll
    for (int m = 16; m > 0; m >>= 1) {
        const float ov0 = __shfl_xor(bestv0, m); const int oi0 = __shfl_xor(besti0, m);
        const float ov1 = __shfl_xor(bestv1, m); const int oi1 = __shfl_xor(besti1, m);
        if (ov0 < bestv0 || (ov0 == bestv0 && oi0 < besti0)) { bestv0 = ov0; besti0 = oi0; }
        if (ov1 < bestv1 || (ov1 == bestv1 && oi1 < besti1)) { bestv1 = ov1; besti1 = oi1; }
    }
    if (cg == 0) {
        row_idx[2 * rg]     = besti0;
        row_idx[2 * rg + 1] = besti1;
        out[(size_t)BD * DD + row0 + 2 * rg]     = (float)besti0;
        out[(size_t)BD * DD + row0 + 2 * rg + 1] = (float)besti1;
    }
    __syncthreads();

    // ---------- Phase C: quantized = R * codes[idx] (rank-2), + loss ----------
    // thread -> (row r) x (g: elements 8g..8g+7)
    {
        const int r = tid >> 4;    // 0..15
        const int g = tid & 15;    // 0..15
        const int qi = row_idx[r];
        const float invn = row_invn[r];
        const float c = row_c[r];
        const float s = row_s[r];
        const size_t grow = (size_t)(row0 + r);
        const float4 q0 = *(const float4*)(codes + (size_t)qi * DD + 8 * g);
        const float4 q1 = *(const float4*)(codes + (size_t)qi * DD + 8 * g + 4);
        const float4 p0 = *(const float4*)(pq + grow * DD + 8 * g);
        const float4 p1 = *(const float4*)(pq + grow * DD + 8 * g + 4);
        float pd = p0.x * q0.x + p0.y * q0.y + p0.z * q0.z + p0.w * q0.w
                 + p1.x * q1.x + p1.y * q1.y + p1.z * q1.z + p1.w * q1.w;
        float ws = q0.x + q0.y + q0.z + q0.w + q1.x + q1.y + q1.z + q1.w;
        #pragma unroll
        for (int m = 8; m > 0; m >>= 1) {
            pd += __shfl_xor(pd, m);
            ws += __shfl_xor(ws, m);
        }
        const float p = pd * invn;           // u . q
        const float w = ws * INV_SQRT_D;     // v . q
        // R q = q + u*(w + s(cw - p)) + v*(-p + s(cp - w))
        const float bu =  w + s * (c * w - p);
        const float bv = -p + s * (c * p - w);
        float4 o0, o1;
        o0.x = q0.x + bu * (p0.x * invn) + bv * INV_SQRT_D;
        o0.y = q0.y + bu * (p0.y * invn) + bv * INV_SQRT_D;
        o0.z = q0.z + bu * (p0.z * invn) + bv * INV_SQRT_D;
        o0.w = q0.w + bu * (p0.w * invn) + bv * INV_SQRT_D;
        o1.x = q1.x + bu * (p1.x * invn) + bv * INV_SQRT_D;
        o1.y = q1.y + bu * (p1.y * invn) + bv * INV_SQRT_D;
        o1.z = q1.z + bu * (p1.z * invn) + bv * INV_SQRT_D;
        o1.w = q1.w + bu * (p1.w * invn) + bv * INV_SQRT_D;
        *(float4*)(out + grow * DD + 8 * g)     = o0;
        *(float4*)(out + grow * DD + 8 * g + 4) = o1;

        const float4 x0 = *(const float4*)(x + grow * DD + 8 * g);
        const float4 x1 = *(const float4*)(x + grow * DD + 8 * g + 4);
        float ls = 0.f, dx;
        dx = x0.x - o0.x; ls = fmaf(dx, dx, ls);
        dx = x0.y - o0.y; ls = fmaf(dx, dx, ls);
        dx = x0.z - o0.z; ls = fmaf(dx, dx, ls);
        dx = x0.w - o0.w; ls = fmaf(dx, dx, ls);
        dx = x1.x - o1.x; ls = fmaf(dx, dx, ls);
        dx = x1.y - o1.y; ls = fmaf(dx, dx, ls);
        dx = x1.z - o1.z; ls = fmaf(dx, dx, ls);
        dx = x1.w - o1.w; ls = fmaf(dx, dx, ls);
        #pragma unroll
        for (int m = 8; m > 0; m >>= 1) ls += __shfl_xor(ls, m);
        if (g == 0) {
            // loss = loss_commit + 0.25*loss_codebook = 1.25 * mean_b ||x - q||^2
            atomicAdd(out + (size_t)BD * DD + BD, ls * (1.25f / (float)BD));
        }
    }
}

extern "C" void kernel_launch(void* const* d_in, const int* in_sizes, int n_in,
                              void* d_out, int out_size, void* d_ws, size_t ws_size,
                              hipStream_t stream) {
    const float* xin   = (const float*)d_in[0];
    const float* prevq = (const float*)d_in[1];
    const float* codes = (const float*)d_in[2];
    float* out = (float*)d_out;
    // zero the loss accumulator slot (harness poisons d_out with 0xAA)
    hipMemsetAsync((void*)(out + (size_t)BD * DD + BD), 0, sizeof(float), stream);
    rq_fused<<<BD / ROWS, 256, 0, stream>>>(xin, prevq, codes, out);
}

// Round 2
// 87.339 us; speedup vs baseline: 1.1118x; 1.1118x over previous
//
#include <hip/hip_runtime.h>

#define BD 4096   // rows
#define CD 256    // codes
#define DD 128    // dim
#define ROWS 8    // rows per block  -> grid 512 = 2 blocks/CU = 8 waves/CU
#define CT 64     // codes per LDS tile
#define PAD 132   // padded LDS row stride (floats); 132*4B keeps float4 alignment

__global__ __launch_bounds__(256) void rq_fused(
    const float* __restrict__ x,
    const float* __restrict__ pq,
    const float* __restrict__ codes,
    float* __restrict__ out)   // [quantized BD*DD | indices BD | loss 1]
{
    __shared__ float xc_s[ROWS * PAD];
    __shared__ float code_s[CT * PAD];
    __shared__ float row_c[ROWS], row_s[ROWS], row_invn[ROWS];
    __shared__ int   row_idx[ROWS];
    __shared__ float loss_s[ROWS];

    const int tid  = threadIdx.x;
    const int wave = tid >> 6;
    const int lane = tid & 63;
    const int row0 = blockIdx.x * ROWS;
    const float INV_SQRT_D = 0.088388347648318447f;  // 1/sqrt(128)

    // ---------- Phase A: per-row rotation  xc = R^T x (rank-2 form) ----------
    // wave w handles rows 2w, 2w+1; each lane holds 2 elements (float2).
    #pragma unroll
    for (int rr = 0; rr < 2; ++rr) {
        const int r = wave * 2 + rr;
        const size_t grow = (size_t)(row0 + r);
        const float2 xv = ((const float2*)(x  + grow * DD))[lane];
        const float2 pv = ((const float2*)(pq + grow * DD))[lane];
        float s0 = pv.x * pv.x + pv.y * pv.y;   // ||pq||^2
        float s1 = pv.x + pv.y;                 // sum pq
        float s2 = xv.x + xv.y;                 // sum x
        float s3 = pv.x * xv.x + pv.y * xv.y;   // pq . x
        #pragma unroll
        for (int m = 32; m > 0; m >>= 1) {
            s0 += __shfl_xor(s0, m);
            s1 += __shfl_xor(s1, m);
            s2 += __shfl_xor(s2, m);
            s3 += __shfl_xor(s3, m);
        }
        const float n    = sqrtf(s0);
        const float invn = 1.0f / fmaxf(n, 1e-6f);     // u = pq * invn
        const float b = s2 * INV_SQRT_D;               // v.x
        const float a = s3 * invn;                     // u.x
        const float c = s1 * invn * INV_SQRT_D;        // u.v
        const float s = 1.0f / (1.0f + c + 1e-6f);
        // R^T x = x + u*(-b + s(cb - a)) + v*(a + s(ca - b))
        const float au = -b + s * (c * b - a);
        const float av =  a + s * (c * a - b);
        const float ux = pv.x * invn, uy = pv.y * invn;
        xc_s[r * PAD + 2 * lane]     = xv.x + au * ux + av * INV_SQRT_D;
        xc_s[r * PAD + 2 * lane + 1] = xv.y + au * uy + av * INV_SQRT_D;
        if (lane == 0) { row_c[r] = c; row_s[r] = s; row_invn[r] = invn; }
    }
    __syncthreads();

    // ---------- Phase B: distances + argmin ----------
    // thread -> (row rg = tid>>5) x (codes cg, cg+32 per tile), 2 accumulators
    const int rg = tid >> 5;   // 0..7 (one row per thread)
    const int cg = tid & 31;   // 0..31
    float bestv0 = 3.4e38f;
    int   besti0 = 0;

    for (int t = 0; t < CD / CT; ++t) {
        // stage 64 codes to LDS, coalesced
        const float4* src = ((const float4*)codes) + (size_t)t * (CT * DD / 4);
        #pragma unroll
        for (int k = 0; k < (CT * DD / 4) / 256; ++k) {   // 8 float4 per thread
            const int f  = k * 256 + tid;
            const int cr = f >> 5, cc = f & 31;
            *(float4*)(code_s + cr * PAD + cc * 4) = src[f];
        }
        __syncthreads();

        float acc0 = 0.f, acc1 = 0.f;
        const float* xr = xc_s + rg * PAD;
        const float* ca = code_s + cg * PAD;
        const float* cb = code_s + (cg + 32) * PAD;
        #pragma unroll
        for (int d4 = 0; d4 < 32; ++d4) {
            const float4 xa = *(const float4*)(xr + d4 * 4);
            const float4 va = *(const float4*)(ca + d4 * 4);
            const float4 vb = *(const float4*)(cb + d4 * 4);
            float dx;
            dx = xa.x - va.x; acc0 = fmaf(dx, dx, acc0);
            dx = xa.y - va.y; acc0 = fmaf(dx, dx, acc0);
            dx = xa.z - va.z; acc0 = fmaf(dx, dx, acc0);
            dx = xa.w - va.w; acc0 = fmaf(dx, dx, acc0);
            dx = xa.x - vb.x; acc1 = fmaf(dx, dx, acc1);
            dx = xa.y - vb.y; acc1 = fmaf(dx, dx, acc1);
            dx = xa.z - vb.z; acc1 = fmaf(dx, dx, acc1);
            dx = xa.w - vb.w; acc1 = fmaf(dx, dx, acc1);
        }
        // fold, ascending index order for first-min tie-break
        const int i0 = t * CT + cg;
        const int i1 = t * CT + cg + 32;
        if (acc0 < bestv0) { bestv0 = acc0; besti0 = i0; }
        if (acc1 < bestv0) { bestv0 = acc1; besti0 = i1; }
        __syncthreads();
    }
    // reduce argmin over the 32 cg lanes (stays within a half-wave)
    #pragma unroll
    for (int m = 16; m > 0; m >>= 1) {
        const float ov0 = __shfl_xor(bestv0, m); const int oi0 = __shfl_xor(besti0, m);
        if (ov0 < bestv0 || (ov0 == bestv0 && oi0 < besti0)) { bestv0 = ov0; besti0 = oi0; }
    }
    if (cg == 0) {
        row_idx[rg] = besti0;
        out[(size_t)BD * DD + row0 + rg] = (float)besti0;
    }
    __syncthreads();

    // ---------- Phase C: quantized = R * codes[idx] (rank-2), + loss ----------
    // thread -> (row r = tid>>5) x (g = tid&31: elements 4g..4g+3)
    {
        const int r = tid >> 5;    // 0..7
        const int g = tid & 31;    // 0..31
        const int qi = row_idx[r];
        const float invn = row_invn[r];
        const float c = row_c[r];
        const float s = row_s[r];
        const size_t grow = (size_t)(row0 + r);
        const float4 q0 = *(const float4*)(codes + (size_t)qi * DD + 4 * g);
        const float4 p0 = *(const float4*)(pq + grow * DD + 4 * g);
        float pd = p0.x * q0.x + p0.y * q0.y + p0.z * q0.z + p0.w * q0.w;
        float ws = q0.x + q0.y + q0.z + q0.w;
        #pragma unroll
        for (int m = 16; m > 0; m >>= 1) {
            pd += __shfl_xor(pd, m);
            ws += __shfl_xor(ws, m);
        }
        const float p = pd * invn;           // u . q
        const float w = ws * INV_SQRT_D;     // v . q
        // R q = q + u*(w + s(cw - p)) + v*(-p + s(cp - w))
        const float bu =  w + s * (c * w - p);
        const float bv = -p + s * (c * p - w);
        float4 o0;
        o0.x = q0.x + bu * (p0.x * invn) + bv * INV_SQRT_D;
        o0.y = q0.y + bu * (p0.y * invn) + bv * INV_SQRT_D;
        o0.z = q0.z + bu * (p0.z * invn) + bv * INV_SQRT_D;
        o0.w = q0.w + bu * (p0.w * invn) + bv * INV_SQRT_D;
        *(float4*)(out + grow * DD + 4 * g) = o0;

        const float4 x0 = *(const float4*)(x + grow * DD + 4 * g);
        float ls = 0.f, dx;
        dx = x0.x - o0.x; ls = fmaf(dx, dx, ls);
        dx = x0.y - o0.y; ls = fmaf(dx, dx, ls);
        dx = x0.z - o0.z; ls = fmaf(dx, dx, ls);
        dx = x0.w - o0.w; ls = fmaf(dx, dx, ls);
        #pragma unroll
        for (int m = 16; m > 0; m >>= 1) ls += __shfl_xor(ls, m);
        if (g == 0) loss_s[r] = ls;
    }
    __syncthreads();
    if (tid == 0) {
        float tot = 0.f;
        #pragma unroll
        for (int r = 0; r < ROWS; ++r) tot += loss_s[r];
        // loss = loss_commit + 0.25*loss_codebook = 1.25 * mean_b ||x - q||^2
        atomicAdd(out + (size_t)BD * DD + BD, tot * (1.25f / (float)BD));
    }
}

extern "C" void kernel_launch(void* const* d_in, const int* in_sizes, int n_in,
                              void* d_out, int out_size, void* d_ws, size_t ws_size,
                              hipStream_t stream) {
    const float* xin   = (const float*)d_in[0];
    const float* prevq = (const float*)d_in[1];
    const float* codes = (const float*)d_in[2];
    float* out = (float*)d_out;
    // zero the loss accumulator slot (harness poisons d_out with 0xAA)
    hipMemsetAsync((void*)(out + (size_t)BD * DD + BD), 0, sizeof(float), stream);
    rq_fused<<<BD / ROWS, 256, 0, stream>>>(xin, prevq, codes, out);
}